// Round 12
// baseline (509.708 us; speedup 1.0000x reference)
//
#include <hip/hip_runtime.h>
#include <hip/hip_fp16.h>
#include <stdint.h>

#define NN 100000
#define EE 3200000
#define DD 128
#define KK 50000
#define NB 32768    // rank buckets (2^15)
#define BB 2048     // band half-width around rank K (band size 2*BB)
#define NBK 391     // coarse edge buckets (256 dst nodes each)
#define TILE 8192   // edges per partition block
#define BMAX 12288  // max edges per coarse bucket staged in LDS (14 sigma)

using u16 = unsigned short;
using u32 = unsigned int;
using u64 = unsigned long long;

typedef _Float16 f16x8 __attribute__((ext_vector_type(8)));
typedef float f32x4 __attribute__((ext_vector_type(4)));

// f32 -> bf16(RNE) -> f32, matching the harness's bf16-quantized reference.
__device__ __forceinline__ float bq(float f) {
  u32 b = __float_as_uint(f);
  b += 0x7FFFu + ((b >> 16) & 1u);
  return __uint_as_float(b & 0xFFFF0000u);
}

__device__ __forceinline__ u32 packh2(float a, float b) {
  return (u32)__half_as_ushort(__float2half(a)) |
         ((u32)__half_as_ushort(__float2half(b)) << 16);
}

// pos from approx rank + band rank (replaces the pos[] array)
__device__ __forceinline__ int posf(int r, const u32* __restrict__ brank) {
  if (r < KK - BB) return r;                       // surely kept
  if (r < KK + BB) {                               // band: exact order decides
    u32 br = brank[r - (KK - BB)];
    return (br < BB) ? (KK - BB + (int)br) : -1;
  }
  return -1;                                       // surely dropped
}

// ---------------- init + W-fragment prep (fused) ----------------
// wfrag[(kstep*8 + ctt)*64 + lane] = W[k][c], k=(lane>>4)*8+j+kstep*32, c=ctt*16+(lane&15)
__global__ void k_init(const float* __restrict__ w, f16x8* __restrict__ wfrag,
                       u32* __restrict__ chist, u32* __restrict__ bcnt,
                       u64* __restrict__ meta) {
  int i = blockIdx.x * 256 + threadIdx.x;
  for (int j = i; j < NB; j += 256 * 256) bcnt[j] = 0u;
  if (i < NBK) chist[i] = 0u;
  if (i == 0) { meta[0] = ~0ull; meta[1] = 0ull; }
  if (i < 2048) {
    int lane = i & 63;
    int ctt = (i >> 6) & 7;
    int kstep = i >> 9;
    int c = ctt * 16 + (lane & 15);
    int kbase = (lane >> 4) * 8 + kstep * 32;
    f16x8 v;
    #pragma unroll
    for (int j = 0; j < 8; ++j) v[j] = (_Float16)w[(kbase + j) * DD + c];
    wfrag[i] = v;
  }
}

// ---------------- coarse dst histogram (LDS-privatized, int4 loads) ----------------
__global__ void k_chist(const int* __restrict__ ei, u32* __restrict__ chist) {
  __shared__ u32 cnt[NBK];
  int t = threadIdx.x;
  int e0 = blockIdx.x * TILE;
  int vcnt = EE - e0; if (vcnt > TILE) vcnt = TILE; // always %4 == 0
  for (int i = t; i < NBK; i += 256) cnt[i] = 0;
  __syncthreads();
  const int4* dv = (const int4*)(ei + EE + e0);
  for (int i = t; i < (vcnt >> 2); i += 256) {
    int4 d = dv[i];
    atomicAdd(&cnt[(u32)d.x >> 8], 1u);
    atomicAdd(&cnt[(u32)d.y >> 8], 1u);
    atomicAdd(&cnt[(u32)d.z >> 8], 1u);
    atomicAdd(&cnt[(u32)d.w >> 8], 1u);
  }
  __syncthreads();
  for (int i = t; i < NBK; i += 256)
    if (cnt[i]) atomicAdd(&chist[i], cnt[i]);
}

// scan coarse histogram -> bucket bases (cbase) + partition cursors (pbcur)
__global__ void k_cscan(const u32* __restrict__ chist, u32* __restrict__ cbase,
                        u32* __restrict__ pbcur) {
  __shared__ u32 buf[2][512];
  int t = threadIdx.x;
  u32 v = (t < NBK) ? chist[t] : 0u;
  int a = 0; buf[0][t] = v; __syncthreads();
  for (int s = 1; s < 512; s <<= 1) {
    buf[1 - a][t] = buf[a][t] + ((t >= s) ? buf[a][t - s] : 0u);
    a = 1 - a; __syncthreads();
  }
  if (t < NBK) { u32 e = buf[a][t] - v; cbase[t] = e; pbcur[t] = e; }
}

// pass 1: partition edges into 391 coarse buckets (coalesced run flushes)
__global__ void k_part1(const int* __restrict__ ei, u32* __restrict__ bcur,
                        u32* __restrict__ ebuf) {
  __shared__ u32 cnt[NBK];
  __shared__ u32 lpos[NBK];
  __shared__ u32 gbase[NBK];
  __shared__ u32 sbuf[TILE];  // 32 KiB packed entries, bucket-sorted
  __shared__ u16 sbid[TILE];  // 16 KiB bucket id per slot
  int t = threadIdx.x;
  int e0 = blockIdx.x * TILE;
  int vcnt = EE - e0; if (vcnt > TILE) vcnt = TILE; // always %4 == 0
  for (int i = t; i < NBK; i += 256) cnt[i] = 0;
  __syncthreads();
  const int4* dv4 = (const int4*)(ei + EE + e0);
  for (int i = t; i < (vcnt >> 2); i += 256) {
    int4 d = dv4[i];
    atomicAdd(&cnt[(u32)d.x >> 8], 1u);
    atomicAdd(&cnt[(u32)d.y >> 8], 1u);
    atomicAdd(&cnt[(u32)d.z >> 8], 1u);
    atomicAdd(&cnt[(u32)d.w >> 8], 1u);
  }
  __syncthreads();
  // exclusive scan cnt -> lpos (wave 0, shfl segments of 64)
  if (t < 64) {
    u32 carry = 0;
    for (int c = 0; c < 7; ++c) {
      int idx = c * 64 + t;
      u32 v = (idx < NBK) ? cnt[idx] : 0u;
      u32 x = v;
      #pragma unroll
      for (int s = 1; s < 64; s <<= 1) {
        u32 y = __shfl_up(x, s);
        if (t >= s) x += y;
      }
      if (idx < NBK) lpos[idx] = x - v + carry;
      carry += __shfl(x, 63);
    }
  }
  __syncthreads();
  for (int i = t; i < NBK; i += 256)
    gbase[i] = cnt[i] ? atomicAdd(&bcur[i], cnt[i]) : 0u;
  // local scatter (bucket-sorted within the tile)
  for (int i = t; i < vcnt; i += 256) {
    int d = ei[EE + e0 + i];
    int s = ei[e0 + i];
    u32 b = (u32)d >> 8;
    u32 p = atomicAdd(&lpos[b], 1u);
    sbuf[p] = ((u32)(d & 255) << 17) | (u32)s;
    sbid[p] = (u16)b;
  }
  __syncthreads();
  // coalesced run flush
  for (int i = t; i < vcnt; i += 256) {
    u32 b = sbid[i];
    u32 lstart = lpos[b] - cnt[b];
    ebuf[gbase[b] + ((u32)i - lstart)] = sbuf[i];
  }
}

// pass 2: fine histogram + scan (deg/offs/dinv) + exact csr, all in LDS
__global__ void k_part2(const u32* __restrict__ ebuf, const u32* __restrict__ cbase,
                        u32* __restrict__ deg, u32* __restrict__ offs,
                        double* __restrict__ dinv64, float* __restrict__ dinv32,
                        int* __restrict__ csr) {
  __shared__ u32 fcnt[256];
  __shared__ u32 buf[2][256];
  __shared__ u32 ncur[256];
  __shared__ u32 scsr[BMAX]; // 48 KiB
  int b = blockIdx.x; int t = threadIdx.x;
  int nbase = b * 256;
  u32 gstart = cbase[b];
  u32 gend = (b + 1 < NBK) ? cbase[b + 1] : (u32)EE;
  u32 cnt = gend - gstart;
  fcnt[t] = 0u;
  __syncthreads();
  for (u32 i = t; i < cnt; i += 256)
    atomicAdd(&fcnt[ebuf[gstart + i] >> 17], 1u);
  __syncthreads();
  // exclusive scan of fcnt
  u32 v = fcnt[t];
  int a = 0; buf[0][t] = v; __syncthreads();
  for (int s = 1; s < 256; s <<= 1) {
    buf[1 - a][t] = buf[a][t] + ((t >= s) ? buf[a][t - s] : 0u);
    a = 1 - a; __syncthreads();
  }
  u32 floc = buf[a][t] - v;
  int node = nbase + t;
  if (node < NN) {
    deg[node] = v;
    offs[node] = gstart + floc;
    double d = 1.0 / sqrt((double)(v + 1u)); // +1 self-loop
    dinv64[node] = d;
    dinv32[node] = (float)d;
  }
  ncur[t] = floc;
  __syncthreads();
  if (cnt <= (u32)BMAX) {
    for (u32 i = t; i < cnt; i += 256) {
      u32 en = ebuf[gstart + i];
      u32 p = atomicAdd(&ncur[en >> 17], 1u);
      scsr[p] = en & 0x1FFFFu;
    }
    __syncthreads();
    for (u32 i = t; i < cnt; i += 256) csr[gstart + i] = (int)scsr[i];
  } else { // statistically unreachable fallback: direct global scatter
    for (u32 i = t; i < cnt; i += 256) {
      u32 en = ebuf[gstart + i];
      u32 p = atomicAdd(&ncur[en >> 17], 1u);
      csr[gstart + p] = (int)(en & 0x1FFFFu);
    }
  }
}

// ------- h = x @ W via MFMA 16x16x32 f16 (f32 accumulate, emit fp16) -------
// Fragment layout + D map (col=lane&15, row=(lane>>4)*4+reg) verified on this
// chip by the k_check self-test across rounds 6-11 (layout is data-independent);
// the check + scalar fallback have been retired.
__global__ void __launch_bounds__(256) k_gemm_mfma(const float* __restrict__ x,
                                                   const f16x8* __restrict__ wfrag,
                                                   u16* __restrict__ hW16) {
  int wid = threadIdx.x >> 6, lane = threadIdx.x & 63;
  int rowbase = blockIdx.x * 32 + (wid & 1) * 16;
  int colgrp = wid >> 1; // 0..1, 64 cols each
  int row = rowbase + (lane & 15);
  int klane = (lane >> 4) * 8;

  f32x4 acc[4] = {{0,0,0,0},{0,0,0,0},{0,0,0,0},{0,0,0,0}};
  const float* xr = x + (size_t)row * DD;
  #pragma unroll
  for (int kstep = 0; kstep < 4; ++kstep) {
    const float4* xp = (const float4*)(xr + klane + kstep * 32);
    float4 v0 = xp[0], v1 = xp[1];
    f16x8 a;
    a[0] = (_Float16)v0.x; a[1] = (_Float16)v0.y;
    a[2] = (_Float16)v0.z; a[3] = (_Float16)v0.w;
    a[4] = (_Float16)v1.x; a[5] = (_Float16)v1.y;
    a[6] = (_Float16)v1.z; a[7] = (_Float16)v1.w;
    #pragma unroll
    for (int ct = 0; ct < 4; ++ct) {
      f16x8 b = wfrag[(kstep * 8 + colgrp * 4 + ct) * 64 + lane];
      acc[ct] = __builtin_amdgcn_mfma_f32_16x16x32_f16(a, b, acc[ct], 0, 0, 0);
    }
  }
  #pragma unroll
  for (int ct = 0; ct < 4; ++ct) {
    int col = colgrp * 64 + ct * 16 + (lane & 15);
    #pragma unroll
    for (int reg = 0; reg < 4; ++reg) {
      int r = rowbase + (lane >> 4) * 4 + reg;
      hW16[(size_t)r * DD + col] = __half_as_ushort(__float2half(acc[ct][reg]));
    }
  }
}

// ---- gather-aggregate: 4 nodes/wave (16 lanes/node, 8 dims/lane via uint4) ----
// grid = NN/16 = 6250 exactly (no partial block); key min/max fused (block
// reduce + 2 global atomics) — replaces the separate k_minmax pass.
__global__ void k_agg(const u32* __restrict__ hw, const float* __restrict__ dinv32,
                      const u32* __restrict__ offs, const u32* __restrict__ deg,
                      const int* __restrict__ csr, const float* __restrict__ bias,
                      u32* __restrict__ hc16, u64* __restrict__ key,
                      float* __restrict__ gate, u64* __restrict__ meta) {
  __shared__ u64 kmn[16], kmx[16];
  int t = threadIdx.x;
  int l4 = t & 15;             // handles dims 8*l4 .. 8*l4+7
  int node = blockIdx.x * 16 + (t >> 4);
  const uint4* hwp = (const uint4*)hw;
  float di = dinv32[node];
  float a0 = 0.f, a1 = 0.f, a2 = 0.f, a3 = 0.f;
  float a4 = 0.f, a5 = 0.f, a6 = 0.f, a7 = 0.f;
  u32 o = offs[node], cnt = deg[node];
  u32 k = 0;
  for (; k + 2 <= cnt; k += 2) {
    int s0 = csr[o + k], s1 = csr[o + k + 1];
    float n0 = dinv32[s0] * di, n1 = dinv32[s1] * di;
    uint4 w0 = hwp[(size_t)s0 * 16 + l4];
    uint4 w1 = hwp[(size_t)s1 * 16 + l4];
    float2 p00 = __half22float2(*(__half2*)&w0.x), p01 = __half22float2(*(__half2*)&w0.y);
    float2 p02 = __half22float2(*(__half2*)&w0.z), p03 = __half22float2(*(__half2*)&w0.w);
    float2 p10 = __half22float2(*(__half2*)&w1.x), p11 = __half22float2(*(__half2*)&w1.y);
    float2 p12 = __half22float2(*(__half2*)&w1.z), p13 = __half22float2(*(__half2*)&w1.w);
    a0 += p00.x * n0 + p10.x * n1;
    a1 += p00.y * n0 + p10.y * n1;
    a2 += p01.x * n0 + p11.x * n1;
    a3 += p01.y * n0 + p11.y * n1;
    a4 += p02.x * n0 + p12.x * n1;
    a5 += p02.y * n0 + p12.y * n1;
    a6 += p03.x * n0 + p13.x * n1;
    a7 += p03.y * n0 + p13.y * n1;
  }
  for (; k < cnt; ++k) {
    int s = csr[o + k];
    float nrm = dinv32[s] * di;
    uint4 wb = hwp[(size_t)s * 16 + l4];
    float2 p0 = __half22float2(*(__half2*)&wb.x), p1 = __half22float2(*(__half2*)&wb.y);
    float2 p2 = __half22float2(*(__half2*)&wb.z), p3 = __half22float2(*(__half2*)&wb.w);
    a0 += p0.x * nrm; a1 += p0.y * nrm; a2 += p1.x * nrm; a3 += p1.y * nrm;
    a4 += p2.x * nrm; a5 += p2.y * nrm; a6 += p3.x * nrm; a7 += p3.y * nrm;
  }
  float di2 = di * di;
  uint4 wb = hwp[(size_t)node * 16 + l4];
  float2 p0 = __half22float2(*(__half2*)&wb.x), p1 = __half22float2(*(__half2*)&wb.y);
  float2 p2 = __half22float2(*(__half2*)&wb.z), p3 = __half22float2(*(__half2*)&wb.w);
  float4 bv0 = ((const float4*)bias)[2 * l4];
  float4 bv1 = ((const float4*)bias)[2 * l4 + 1];
  a0 += p0.x * di2 + bv0.x;
  a1 += p0.y * di2 + bv0.y;
  a2 += p1.x * di2 + bv0.z;
  a3 += p1.y * di2 + bv0.w;
  a4 += p2.x * di2 + bv1.x;
  a5 += p2.y * di2 + bv1.y;
  a6 += p3.x * di2 + bv1.z;
  a7 += p3.y * di2 + bv1.w;
  uint4 out;
  out.x = packh2(a0, a1); out.y = packh2(a2, a3);
  out.z = packh2(a4, a5); out.w = packh2(a6, a7);
  ((uint4*)hc16)[(size_t)node * 16 + l4] = out;
  float ss = a0 * a0 + a1 * a1 + a2 * a2 + a3 * a3
           + a4 * a4 + a5 * a5 + a6 * a6 + a7 * a7;
  #pragma unroll
  for (int off = 8; off > 0; off >>= 1) ss += __shfl_xor(ss, off);
  if (l4 == 0) {
    // approx key: f32 ss bits (monotone in score, ss >= 0);
    // low 17 bits = (0x1FFFF - node) => lower index wins ties
    u32 sb = __float_as_uint(ss);
    u64 kk = ((u64)sb << 17) | (u64)(0x1FFFF - node);
    key[node] = kk;
    gate[node] = tanhf(sqrtf(ss + 1e-12f));
    kmn[t >> 4] = kk;
    kmx[t >> 4] = kk;
  }
  __syncthreads();
  if (t == 0) {
    u64 mn = ~0ull, mx = 0ull;
    #pragma unroll
    for (int g = 0; g < 16; ++g) {
      if (kmn[g] < mn) mn = kmn[g];
      if (kmx[g] > mx) mx = kmx[g];
    }
    atomicMin(&meta[0], mn);
    atomicMax(&meta[1], mx);
  }
}

// ---------------- exact bucket-rank (approx keys -> full rank) ----------------
__device__ __forceinline__ u32 bshift(u64 kmin, u64 kmax) {
  u64 range = kmax - kmin;
  int bits = 64 - __clzll(range | 1ull);
  return (u32)(bits > 15 ? bits - 15 : 0); // 2^15 buckets
}

__global__ void k_hist(const u64* __restrict__ key, const u64* __restrict__ meta,
                       u32* __restrict__ barr, u32* __restrict__ bcnt) {
  int i = blockIdx.x * blockDim.x + threadIdx.x;
  if (i >= NN) return;
  u64 kmin = meta[0];
  u32 sh = bshift(kmin, meta[1]);
  u32 b = (u32)((key[i] - kmin) >> sh);
  barr[i] = b;
  atomicAdd(&bcnt[b], 1u);
}

// fused suffix-scan over NB buckets: one block, 1024 threads, 32 chunks w/ carry
__global__ void k_bscan(const u32* __restrict__ bcnt, u32* __restrict__ base,
                        u32* __restrict__ bcur) {
  __shared__ u32 buf[2][1024];
  int t = threadIdx.x;
  u32 carry = 0;
  for (int c = 0; c < NB / 1024; ++c) {
    int r = c * 1024 + t;
    int b = NB - 1 - r;
    u32 v = bcnt[b];
    int a = 0; buf[0][t] = v; __syncthreads();
    for (int s = 1; s < 1024; s <<= 1) {
      buf[1 - a][t] = buf[a][t] + ((t >= s) ? buf[a][t - s] : 0u);
      a = 1 - a; __syncthreads();
    }
    u32 inc = buf[a][t];
    u32 bs = inc - v + carry;           // suffix-exclusive count of higher keys
    base[b] = bs;
    bcur[b] = NN - bs - v;              // storage offset
    u32 tot = buf[a][1023];
    __syncthreads();                    // all reads done before next chunk writes
    carry += tot;
  }
}

__global__ void k_bscatter(const u32* __restrict__ barr, u32* __restrict__ bcur,
                           u32* __restrict__ blist) {
  int i = blockIdx.x * blockDim.x + threadIdx.x;
  if (i >= NN) return;
  u32 p = atomicAdd(&bcur[barr[i]], 1u);
  blist[p] = (u32)i;
}

// rank + in-band selection fused
__global__ void k_rank2(const u64* __restrict__ key, const u32* __restrict__ barr,
                        const u32* __restrict__ bcnt, const u32* __restrict__ base,
                        const u32* __restrict__ blist, int* __restrict__ arank,
                        u32* __restrict__ bandNode) {
  int i = blockIdx.x * blockDim.x + threadIdx.x;
  if (i >= NN) return;
  u32 b = barr[i];
  u64 ki = key[i];
  u32 bs = base[b], cnt = bcnt[b];
  u32 off = NN - bs - cnt;
  u32 gt = 0;
  for (u32 j = 0; j < cnt; ++j) gt += (key[blist[off + j]] > ki) ? 1u : 0u;
  int r = (int)(bs + gt);
  arank[i] = r; // full approx rank (a permutation of 0..NN-1)
  int rb = r - (KK - BB);
  if (rb >= 0 && rb < 2 * BB) bandNode[rb] = (u32)i;
}

// ---------------- exact band repair ----------------
// exact f64 rescore via linearity: a = (sum_s wgt_s * x_s) @ W + bias
__global__ void k_bscore(const u32* __restrict__ bandNode,
                         const float* __restrict__ x, const float* __restrict__ w,
                         const double* __restrict__ dinv64,
                         const u32* __restrict__ offs, const u32* __restrict__ deg,
                         const int* __restrict__ csr, const float* __restrict__ bias,
                         u64* __restrict__ ekey) {
  __shared__ double zsh[4][DD]; // 4 KiB
  int wid = threadIdx.x >> 6;
  int lane = threadIdx.x & 63;
  int slot = blockIdx.x * 4 + wid;
  int node = (int)bandNode[slot];
  double di = dinv64[node];
  double z0 = 0.0, z1 = 0.0;
  u32 o = offs[node], cnt = deg[node];
  for (u32 k = 0; k <= cnt; ++k) { // last iter = self row
    int s = (k < cnt) ? csr[o + k] : node;
    double wgt = (k < cnt) ? (dinv64[s] * di) : (di * di);
    float2 xv = ((const float2*)x)[(size_t)s * 64 + lane];
    z0 += (double)xv.x * wgt;
    z1 += (double)xv.y * wgt;
  }
  zsh[wid][2 * lane] = z0;
  zsh[wid][2 * lane + 1] = z1;
  __syncthreads();
  float2 bv = ((const float2*)bias)[lane];
  double a0 = (double)bv.x, a1 = (double)bv.y;
  for (int kk = 0; kk < DD; ++kk) {
    double zk = zsh[wid][kk];
    float2 wv = ((const float2*)w)[kk * 64 + lane];
    a0 += zk * (double)wv.x;
    a1 += zk * (double)wv.y;
  }
  double ss = a0 * a0 + a1 * a1;
  #pragma unroll
  for (int off = 32; off > 0; off >>= 1) ss += __shfl_xor(ss, off);
  if (lane == 0) {
    double sc = sqrt(ss + 1e-12);
    u64 bits = (u64)__double_as_longlong(sc);
    ekey[slot] = (bits & ~0x1FFFFull) | (u64)(0x1FFFF - node);
  }
}

__global__ void k_bandrank(const u64* __restrict__ ekey, u32* __restrict__ brank) {
  __shared__ u64 sk[2 * BB]; // 32 KiB
  int t = threadIdx.x;
  for (int j = t; j < 2 * BB; j += 256) sk[j] = ekey[j];
  __syncthreads();
  int idx = blockIdx.x * 256 + t;
  u64 kk = sk[idx];
  u32 c = 0;
  for (int j = 0; j < 2 * BB; ++j) c += (sk[j] > kk) ? 1u : 0u;
  brank[idx] = c;
}

// ---------------- outputs (f32, bf16-RNE-quantized) ----------------
// 2 elems/thread: u32 (half2) load from hc16, float2 store; pos inlined
__global__ void k_xout(const u32* __restrict__ hc16, const float* __restrict__ gate,
                       const int* __restrict__ arank, const u32* __restrict__ brank,
                       float* __restrict__ outx) {
  int id = blockIdx.x * blockDim.x + threadIdx.x;
  if (id >= NN * 64) return;
  int i = id >> 6, d2 = id & 63;
  int p = posf(arank[i], brank);
  if (p < 0) return;
  float g = gate[i];
  u32 hv = hc16[(size_t)i * 64 + d2];
  float2 v = __half22float2(*(__half2*)&hv);
  float2 out = make_float2(bq(v.x * g), bq(v.y * g));
  ((float2*)outx)[(size_t)p * 64 + d2] = out;
}

// 2 edges/thread; pos inlined
__global__ void k_edges(const int* __restrict__ ei, const int* __restrict__ arank,
                        const u32* __restrict__ brank,
                        float* __restrict__ osrc, float* __restrict__ odst,
                        float* __restrict__ omask) {
  int e2 = blockIdx.x * blockDim.x + threadIdx.x;
  if (e2 >= EE / 2) return;
  int2 sv = ((const int2*)ei)[e2];
  int2 dv = ((const int2*)(ei + EE))[e2];
  int ps0 = posf(arank[sv.x], brank), pd0 = posf(arank[dv.x], brank);
  int ps1 = posf(arank[sv.y], brank), pd1 = posf(arank[dv.y], brank);
  bool m0 = (ps0 >= 0) && (pd0 >= 0);
  bool m1 = (ps1 >= 0) && (pd1 >= 0);
  ((float2*)osrc)[e2] = make_float2(m0 ? bq((float)ps0) : -1.0f,
                                    m1 ? bq((float)ps1) : -1.0f);
  ((float2*)odst)[e2] = make_float2(m0 ? bq((float)pd0) : -1.0f,
                                    m1 ? bq((float)pd1) : -1.0f);
  ((float2*)omask)[e2] = make_float2(m0 ? 1.0f : 0.0f, m1 ? 1.0f : 0.0f);
}

// ---------------- driver (15 dispatches) ----------------
extern "C" void kernel_launch(void* const* d_in, const int* in_sizes, int n_in,
                              void* d_out, int out_size, void* d_ws, size_t ws_size,
                              hipStream_t stream) {
  const float* x    = (const float*)d_in[0];
  const int*   ei   = (const int*)d_in[1];
  const float* w    = (const float*)d_in[2];
  const float* bias = (const float*)d_in[3];
  float* outx = (float*)d_out;
  char* ws = (char*)d_ws;

  size_t off = 0;
  auto alloc = [&](size_t b) -> void* {
    void* p = ws + off; off += (b + 255) & ~(size_t)255; return p;
  };
  u16*    hW16   = (u16*)alloc((size_t)NN * DD * 2);
  u32*    hc16   = (u32*)alloc((size_t)NN * DD * 2);
  double* dinv64 = (double*)alloc((size_t)NN * 8);
  float*  dinv32 = (float*)alloc((size_t)NN * 4);
  float*  gate   = (float*)alloc((size_t)NN * 4);
  u64*    key    = (u64*)alloc((size_t)NN * 8);
  u32*    deg    = (u32*)alloc((size_t)NN * 4);
  u32*    offs   = (u32*)alloc((size_t)NN * 4);
  int*    csr    = (int*)alloc((size_t)EE * 4);
  u32*    ebuf   = (u32*)alloc((size_t)EE * 4);
  u32*    chist  = (u32*)alloc((size_t)NBK * 4);
  u32*    cbase  = (u32*)alloc((size_t)NBK * 4);
  u32*    pbcur  = (u32*)alloc((size_t)NBK * 4);
  int*    arank  = (int*)alloc((size_t)NN * 4);
  u64*    meta   = (u64*)alloc(4 * 8);
  u32*    bcnt   = (u32*)alloc((size_t)NB * 4);
  u32*    base   = (u32*)alloc((size_t)NB * 4);
  u32*    bcur   = (u32*)alloc((size_t)NB * 4);
  u32*    barr   = (u32*)alloc((size_t)NN * 4);
  u32*    blist  = (u32*)alloc((size_t)NN * 4);
  u32*    bandNode = (u32*)alloc((size_t)2 * BB * 4);
  u64*    ekey     = (u64*)alloc((size_t)2 * BB * 8);
  u32*    brank    = (u32*)alloc((size_t)2 * BB * 4);
  f16x8*  wfrag    = (f16x8*)alloc((size_t)2048 * 16);

  k_init<<<256, 256, 0, stream>>>(w, wfrag, chist, bcnt, meta);
  // CSR build: coarse hist -> scan -> 2-pass partition (no global atomic storms)
  k_chist<<<(EE + TILE - 1) / TILE, 256, 0, stream>>>(ei, chist);
  k_cscan<<<1, 512, 0, stream>>>(chist, cbase, pbcur);
  k_part1<<<(EE + TILE - 1) / TILE, 256, 0, stream>>>(ei, pbcur, ebuf);
  k_part2<<<NBK, 256, 0, stream>>>(ebuf, cbase, deg, offs, dinv64, dinv32, csr);
  // GEMM via MFMA (layout verified rounds 6-11; fallback retired)
  k_gemm_mfma<<<NN / 32, 256, 0, stream>>>(x, wfrag, hW16);
  // gather-aggregate + keys + fused min/max
  k_agg<<<NN / 16, 256, 0, stream>>>((const u32*)hW16, dinv32, offs, deg, csr,
                                     bias, hc16, key, gate, meta);
  k_hist<<<(NN + 255) / 256, 256, 0, stream>>>(key, meta, barr, bcnt);
  k_bscan<<<1, 1024, 0, stream>>>(bcnt, base, bcur);
  k_bscatter<<<(NN + 255) / 256, 256, 0, stream>>>(barr, bcur, blist);
  k_rank2<<<(NN + 255) / 256, 256, 0, stream>>>(key, barr, bcnt, base, blist, arank,
                                                bandNode);
  // exact band repair (f64 truth via linearity)
  k_bscore<<<(2 * BB) / 4, 256, 0, stream>>>(bandNode, x, w, dinv64, offs, deg, csr,
                                             bias, ekey);
  k_bandrank<<<(2 * BB) / 256, 256, 0, stream>>>(ekey, brank);
  k_xout<<<(NN * 64 + 255) / 256, 256, 0, stream>>>(hc16, gate, arank, brank, outx);
  float* oei = outx + (size_t)KK * DD;
  k_edges<<<(EE / 2 + 255) / 256, 256, 0, stream>>>(ei, arank, brank, oei, oei + EE,
                                                    oei + 2 * (size_t)EE);
}

// Round 13
// 437.468 us; speedup vs baseline: 1.1651x; 1.1651x over previous
//
#include <hip/hip_runtime.h>
#include <hip/hip_fp16.h>
#include <stdint.h>

#define NN 100000
#define EE 3200000
#define DD 128
#define KK 50000
#define NB 32768    // rank buckets (2^15)
#define BB 2048     // band half-width around rank K (band size 2*BB)
#define NBK 391     // coarse edge buckets (256 dst nodes each)
#define TILE 8192   // edges per partition block
#define BMAX 12288  // max edges per coarse bucket staged in LDS (14 sigma)
#define NBLK 391    // ceil(NN / 256)

using u16 = unsigned short;
using u32 = unsigned int;
using u64 = unsigned long long;

typedef _Float16 f16x8 __attribute__((ext_vector_type(8)));
typedef float f32x4 __attribute__((ext_vector_type(4)));

// f32 -> bf16(RNE) -> f32, matching the harness's bf16-quantized reference.
__device__ __forceinline__ float bq(float f) {
  u32 b = __float_as_uint(f);
  b += 0x7FFFu + ((b >> 16) & 1u);
  return __uint_as_float(b & 0xFFFF0000u);
}

__device__ __forceinline__ u32 packh2(float a, float b) {
  return (u32)__half_as_ushort(__float2half(a)) |
         ((u32)__half_as_ushort(__float2half(b)) << 16);
}

// pos from approx rank + band rank (replaces the pos[] array)
__device__ __forceinline__ int posf(int r, const u32* __restrict__ brank) {
  if (r < KK - BB) return r;                       // surely kept
  if (r < KK + BB) {                               // band: exact order decides
    u32 br = brank[r - (KK - BB)];
    return (br < BB) ? (KK - BB + (int)br) : -1;
  }
  return -1;                                       // surely dropped
}

// ---------------- init + W-fragment prep (fused) ----------------
// wfrag[(kstep*8 + ctt)*64 + lane] = W[k][c], k=(lane>>4)*8+j+kstep*32, c=ctt*16+(lane&15)
__global__ void k_init(const float* __restrict__ w, f16x8* __restrict__ wfrag,
                       u32* __restrict__ chist, u32* __restrict__ bcnt,
                       u64* __restrict__ meta) {
  int i = blockIdx.x * 256 + threadIdx.x;
  for (int j = i; j < NB; j += 256 * 256) bcnt[j] = 0u;
  if (i < NBK) chist[i] = 0u;
  if (i == 0) { meta[0] = ~0ull; meta[1] = 0ull; }
  if (i < 2048) {
    int lane = i & 63;
    int ctt = (i >> 6) & 7;
    int kstep = i >> 9;
    int c = ctt * 16 + (lane & 15);
    int kbase = (lane >> 4) * 8 + kstep * 32;
    f16x8 v;
    #pragma unroll
    for (int j = 0; j < 8; ++j) v[j] = (_Float16)w[(kbase + j) * DD + c];
    wfrag[i] = v;
  }
}

// ---------------- coarse dst histogram (LDS-privatized, int4 loads) ----------------
__global__ void k_chist(const int* __restrict__ ei, u32* __restrict__ chist) {
  __shared__ u32 cnt[NBK];
  int t = threadIdx.x;
  int e0 = blockIdx.x * TILE;
  int vcnt = EE - e0; if (vcnt > TILE) vcnt = TILE; // always %4 == 0
  for (int i = t; i < NBK; i += 256) cnt[i] = 0;
  __syncthreads();
  const int4* dv = (const int4*)(ei + EE + e0);
  for (int i = t; i < (vcnt >> 2); i += 256) {
    int4 d = dv[i];
    atomicAdd(&cnt[(u32)d.x >> 8], 1u);
    atomicAdd(&cnt[(u32)d.y >> 8], 1u);
    atomicAdd(&cnt[(u32)d.z >> 8], 1u);
    atomicAdd(&cnt[(u32)d.w >> 8], 1u);
  }
  __syncthreads();
  for (int i = t; i < NBK; i += 256)
    if (cnt[i]) atomicAdd(&chist[i], cnt[i]);
}

// scan coarse histogram -> bucket bases (cbase) + partition cursors (pbcur)
__global__ void k_cscan(const u32* __restrict__ chist, u32* __restrict__ cbase,
                        u32* __restrict__ pbcur) {
  __shared__ u32 buf[2][512];
  int t = threadIdx.x;
  u32 v = (t < NBK) ? chist[t] : 0u;
  int a = 0; buf[0][t] = v; __syncthreads();
  for (int s = 1; s < 512; s <<= 1) {
    buf[1 - a][t] = buf[a][t] + ((t >= s) ? buf[a][t - s] : 0u);
    a = 1 - a; __syncthreads();
  }
  if (t < NBK) { u32 e = buf[a][t] - v; cbase[t] = e; pbcur[t] = e; }
}

// pass 1: partition edges into 391 coarse buckets (coalesced run flushes)
__global__ void k_part1(const int* __restrict__ ei, u32* __restrict__ bcur,
                        u32* __restrict__ ebuf) {
  __shared__ u32 cnt[NBK];
  __shared__ u32 lpos[NBK];
  __shared__ u32 gbase[NBK];
  __shared__ u32 sbuf[TILE];  // 32 KiB packed entries, bucket-sorted
  __shared__ u16 sbid[TILE];  // 16 KiB bucket id per slot
  int t = threadIdx.x;
  int e0 = blockIdx.x * TILE;
  int vcnt = EE - e0; if (vcnt > TILE) vcnt = TILE; // always %4 == 0
  for (int i = t; i < NBK; i += 256) cnt[i] = 0;
  __syncthreads();
  const int4* dv4 = (const int4*)(ei + EE + e0);
  for (int i = t; i < (vcnt >> 2); i += 256) {
    int4 d = dv4[i];
    atomicAdd(&cnt[(u32)d.x >> 8], 1u);
    atomicAdd(&cnt[(u32)d.y >> 8], 1u);
    atomicAdd(&cnt[(u32)d.z >> 8], 1u);
    atomicAdd(&cnt[(u32)d.w >> 8], 1u);
  }
  __syncthreads();
  // exclusive scan cnt -> lpos (wave 0, shfl segments of 64)
  if (t < 64) {
    u32 carry = 0;
    for (int c = 0; c < 7; ++c) {
      int idx = c * 64 + t;
      u32 v = (idx < NBK) ? cnt[idx] : 0u;
      u32 x = v;
      #pragma unroll
      for (int s = 1; s < 64; s <<= 1) {
        u32 y = __shfl_up(x, s);
        if (t >= s) x += y;
      }
      if (idx < NBK) lpos[idx] = x - v + carry;
      carry += __shfl(x, 63);
    }
  }
  __syncthreads();
  for (int i = t; i < NBK; i += 256)
    gbase[i] = cnt[i] ? atomicAdd(&bcur[i], cnt[i]) : 0u;
  // local scatter (bucket-sorted within the tile)
  for (int i = t; i < vcnt; i += 256) {
    int d = ei[EE + e0 + i];
    int s = ei[e0 + i];
    u32 b = (u32)d >> 8;
    u32 p = atomicAdd(&lpos[b], 1u);
    sbuf[p] = ((u32)(d & 255) << 17) | (u32)s;
    sbid[p] = (u16)b;
  }
  __syncthreads();
  // coalesced run flush
  for (int i = t; i < vcnt; i += 256) {
    u32 b = sbid[i];
    u32 lstart = lpos[b] - cnt[b];
    ebuf[gbase[b] + ((u32)i - lstart)] = sbuf[i];
  }
}

// pass 2: fine histogram + scan (deg/offs/dinv) + exact csr, all in LDS
__global__ void k_part2(const u32* __restrict__ ebuf, const u32* __restrict__ cbase,
                        u32* __restrict__ deg, u32* __restrict__ offs,
                        double* __restrict__ dinv64, float* __restrict__ dinv32,
                        int* __restrict__ csr) {
  __shared__ u32 fcnt[256];
  __shared__ u32 buf[2][256];
  __shared__ u32 ncur[256];
  __shared__ u32 scsr[BMAX]; // 48 KiB
  int b = blockIdx.x; int t = threadIdx.x;
  int nbase = b * 256;
  u32 gstart = cbase[b];
  u32 gend = (b + 1 < NBK) ? cbase[b + 1] : (u32)EE;
  u32 cnt = gend - gstart;
  fcnt[t] = 0u;
  __syncthreads();
  for (u32 i = t; i < cnt; i += 256)
    atomicAdd(&fcnt[ebuf[gstart + i] >> 17], 1u);
  __syncthreads();
  // exclusive scan of fcnt
  u32 v = fcnt[t];
  int a = 0; buf[0][t] = v; __syncthreads();
  for (int s = 1; s < 256; s <<= 1) {
    buf[1 - a][t] = buf[a][t] + ((t >= s) ? buf[a][t - s] : 0u);
    a = 1 - a; __syncthreads();
  }
  u32 floc = buf[a][t] - v;
  int node = nbase + t;
  if (node < NN) {
    deg[node] = v;
    offs[node] = gstart + floc;
    double d = 1.0 / sqrt((double)(v + 1u)); // +1 self-loop
    dinv64[node] = d;
    dinv32[node] = (float)d;
  }
  ncur[t] = floc;
  __syncthreads();
  if (cnt <= (u32)BMAX) {
    for (u32 i = t; i < cnt; i += 256) {
      u32 en = ebuf[gstart + i];
      u32 p = atomicAdd(&ncur[en >> 17], 1u);
      scsr[p] = en & 0x1FFFFu;
    }
    __syncthreads();
    for (u32 i = t; i < cnt; i += 256) csr[gstart + i] = (int)scsr[i];
  } else { // statistically unreachable fallback: direct global scatter
    for (u32 i = t; i < cnt; i += 256) {
      u32 en = ebuf[gstart + i];
      u32 p = atomicAdd(&ncur[en >> 17], 1u);
      csr[gstart + p] = (int)(en & 0x1FFFFu);
    }
  }
}

// ------- h = x @ W via MFMA 16x16x32 f16 (f32 accumulate, emit fp16) -------
// Fragment layout + D map (col=lane&15, row=(lane>>4)*4+reg) verified on this
// chip by the k_check self-test across rounds 6-11 (layout is data-independent).
__global__ void __launch_bounds__(256) k_gemm_mfma(const float* __restrict__ x,
                                                   const f16x8* __restrict__ wfrag,
                                                   u16* __restrict__ hW16) {
  int wid = threadIdx.x >> 6, lane = threadIdx.x & 63;
  int rowbase = blockIdx.x * 32 + (wid & 1) * 16;
  int colgrp = wid >> 1; // 0..1, 64 cols each
  int row = rowbase + (lane & 15);
  int klane = (lane >> 4) * 8;

  f32x4 acc[4] = {{0,0,0,0},{0,0,0,0},{0,0,0,0},{0,0,0,0}};
  const float* xr = x + (size_t)row * DD;
  #pragma unroll
  for (int kstep = 0; kstep < 4; ++kstep) {
    const float4* xp = (const float4*)(xr + klane + kstep * 32);
    float4 v0 = xp[0], v1 = xp[1];
    f16x8 a;
    a[0] = (_Float16)v0.x; a[1] = (_Float16)v0.y;
    a[2] = (_Float16)v0.z; a[3] = (_Float16)v0.w;
    a[4] = (_Float16)v1.x; a[5] = (_Float16)v1.y;
    a[6] = (_Float16)v1.z; a[7] = (_Float16)v1.w;
    #pragma unroll
    for (int ct = 0; ct < 4; ++ct) {
      f16x8 b = wfrag[(kstep * 8 + colgrp * 4 + ct) * 64 + lane];
      acc[ct] = __builtin_amdgcn_mfma_f32_16x16x32_f16(a, b, acc[ct], 0, 0, 0);
    }
  }
  #pragma unroll
  for (int ct = 0; ct < 4; ++ct) {
    int col = colgrp * 64 + ct * 16 + (lane & 15);
    #pragma unroll
    for (int reg = 0; reg < 4; ++reg) {
      int r = rowbase + (lane >> 4) * 4 + reg;
      hW16[(size_t)r * DD + col] = __half_as_ushort(__float2half(acc[ct][reg]));
    }
  }
}

// ---- gather-aggregate: 4 nodes/wave (16 lanes/node, 8 dims/lane via uint4) ----
// NO trailing barrier/fusion: waves retire as they finish (round-12 lesson:
// a block-wide reduce here cost +80us by parking waves at the barrier).
__global__ void k_agg(const u32* __restrict__ hw, const float* __restrict__ dinv32,
                      const u32* __restrict__ offs, const u32* __restrict__ deg,
                      const int* __restrict__ csr, const float* __restrict__ bias,
                      u32* __restrict__ hc16, u64* __restrict__ key,
                      float* __restrict__ gate) {
  int t = threadIdx.x;
  int l4 = t & 15;             // handles dims 8*l4 .. 8*l4+7
  int node = blockIdx.x * 16 + (t >> 4);
  if (node >= NN) return;
  const uint4* hwp = (const uint4*)hw;
  float di = dinv32[node];
  float a0 = 0.f, a1 = 0.f, a2 = 0.f, a3 = 0.f;
  float a4 = 0.f, a5 = 0.f, a6 = 0.f, a7 = 0.f;
  u32 o = offs[node], cnt = deg[node];
  u32 k = 0;
  for (; k + 2 <= cnt; k += 2) {
    int s0 = csr[o + k], s1 = csr[o + k + 1];
    float n0 = dinv32[s0] * di, n1 = dinv32[s1] * di;
    uint4 w0 = hwp[(size_t)s0 * 16 + l4];
    uint4 w1 = hwp[(size_t)s1 * 16 + l4];
    float2 p00 = __half22float2(*(__half2*)&w0.x), p01 = __half22float2(*(__half2*)&w0.y);
    float2 p02 = __half22float2(*(__half2*)&w0.z), p03 = __half22float2(*(__half2*)&w0.w);
    float2 p10 = __half22float2(*(__half2*)&w1.x), p11 = __half22float2(*(__half2*)&w1.y);
    float2 p12 = __half22float2(*(__half2*)&w1.z), p13 = __half22float2(*(__half2*)&w1.w);
    a0 += p00.x * n0 + p10.x * n1;
    a1 += p00.y * n0 + p10.y * n1;
    a2 += p01.x * n0 + p11.x * n1;
    a3 += p01.y * n0 + p11.y * n1;
    a4 += p02.x * n0 + p12.x * n1;
    a5 += p02.y * n0 + p12.y * n1;
    a6 += p03.x * n0 + p13.x * n1;
    a7 += p03.y * n0 + p13.y * n1;
  }
  for (; k < cnt; ++k) {
    int s = csr[o + k];
    float nrm = dinv32[s] * di;
    uint4 wb = hwp[(size_t)s * 16 + l4];
    float2 p0 = __half22float2(*(__half2*)&wb.x), p1 = __half22float2(*(__half2*)&wb.y);
    float2 p2 = __half22float2(*(__half2*)&wb.z), p3 = __half22float2(*(__half2*)&wb.w);
    a0 += p0.x * nrm; a1 += p0.y * nrm; a2 += p1.x * nrm; a3 += p1.y * nrm;
    a4 += p2.x * nrm; a5 += p2.y * nrm; a6 += p3.x * nrm; a7 += p3.y * nrm;
  }
  float di2 = di * di;
  uint4 wb = hwp[(size_t)node * 16 + l4];
  float2 p0 = __half22float2(*(__half2*)&wb.x), p1 = __half22float2(*(__half2*)&wb.y);
  float2 p2 = __half22float2(*(__half2*)&wb.z), p3 = __half22float2(*(__half2*)&wb.w);
  float4 bv0 = ((const float4*)bias)[2 * l4];
  float4 bv1 = ((const float4*)bias)[2 * l4 + 1];
  a0 += p0.x * di2 + bv0.x;
  a1 += p0.y * di2 + bv0.y;
  a2 += p1.x * di2 + bv0.z;
  a3 += p1.y * di2 + bv0.w;
  a4 += p2.x * di2 + bv1.x;
  a5 += p2.y * di2 + bv1.y;
  a6 += p3.x * di2 + bv1.z;
  a7 += p3.y * di2 + bv1.w;
  uint4 out;
  out.x = packh2(a0, a1); out.y = packh2(a2, a3);
  out.z = packh2(a4, a5); out.w = packh2(a6, a7);
  ((uint4*)hc16)[(size_t)node * 16 + l4] = out;
  float ss = a0 * a0 + a1 * a1 + a2 * a2 + a3 * a3
           + a4 * a4 + a5 * a5 + a6 * a6 + a7 * a7;
  #pragma unroll
  for (int off = 8; off > 0; off >>= 1) ss += __shfl_xor(ss, off);
  if (l4 == 0) {
    // approx key: f32 ss bits (monotone in score, ss >= 0);
    // low 17 bits = (0x1FFFF - node) => lower index wins ties
    u32 sb = __float_as_uint(ss);
    key[node] = ((u64)sb << 17) | (u64)(0x1FFFF - node);
    gate[node] = tanhf(sqrtf(ss + 1e-12f));
  }
}

// ---------------- key min/max (separate pass; see round-12 lesson) ----------------
__global__ void k_minmax(const u64* __restrict__ key, u64* __restrict__ meta) {
  __shared__ u64 smn[256], smx[256];
  int t = threadIdx.x; int i = blockIdx.x * 256 + t;
  u64 v = (i < NN) ? key[i] : key[0];
  smn[t] = v; smx[t] = v; __syncthreads();
  for (int s = 128; s > 0; s >>= 1) {
    if (t < s) {
      if (smn[t + s] < smn[t]) smn[t] = smn[t + s];
      if (smx[t + s] > smx[t]) smx[t] = smx[t + s];
    }
    __syncthreads();
  }
  if (t == 0) { atomicMin(&meta[0], smn[0]); atomicMax(&meta[1], smx[0]); }
}

// ---------------- exact bucket-rank (approx keys -> full rank) ----------------
__device__ __forceinline__ u32 bshift(u64 kmin, u64 kmax) {
  u64 range = kmax - kmin;
  int bits = 64 - __clzll(range | 1ull);
  return (u32)(bits > 15 ? bits - 15 : 0); // 2^15 buckets
}

__global__ void k_hist(const u64* __restrict__ key, const u64* __restrict__ meta,
                       u32* __restrict__ barr, u32* __restrict__ bcnt) {
  int i = blockIdx.x * blockDim.x + threadIdx.x;
  if (i >= NN) return;
  u64 kmin = meta[0];
  u32 sh = bshift(kmin, meta[1]);
  u32 b = (u32)((key[i] - kmin) >> sh);
  barr[i] = b;
  atomicAdd(&bcnt[b], 1u);
}

// fused suffix-scan over NB buckets: one block, 1024 threads, 32 chunks w/ carry
__global__ void k_bscan(const u32* __restrict__ bcnt, u32* __restrict__ base,
                        u32* __restrict__ bcur) {
  __shared__ u32 buf[2][1024];
  int t = threadIdx.x;
  u32 carry = 0;
  for (int c = 0; c < NB / 1024; ++c) {
    int r = c * 1024 + t;
    int b = NB - 1 - r;
    u32 v = bcnt[b];
    int a = 0; buf[0][t] = v; __syncthreads();
    for (int s = 1; s < 1024; s <<= 1) {
      buf[1 - a][t] = buf[a][t] + ((t >= s) ? buf[a][t - s] : 0u);
      a = 1 - a; __syncthreads();
    }
    u32 inc = buf[a][t];
    u32 bs = inc - v + carry;           // suffix-exclusive count of higher keys
    base[b] = bs;
    bcur[b] = NN - bs - v;              // storage offset
    u32 tot = buf[a][1023];
    __syncthreads();                    // all reads done before next chunk writes
    carry += tot;
  }
}

__global__ void k_bscatter(const u32* __restrict__ barr, u32* __restrict__ bcur,
                           u32* __restrict__ blist) {
  int i = blockIdx.x * blockDim.x + threadIdx.x;
  if (i >= NN) return;
  u32 p = atomicAdd(&bcur[barr[i]], 1u);
  blist[p] = (u32)i;
}

// rank + in-band selection fused
__global__ void k_rank2(const u64* __restrict__ key, const u32* __restrict__ barr,
                        const u32* __restrict__ bcnt, const u32* __restrict__ base,
                        const u32* __restrict__ blist, int* __restrict__ arank,
                        u32* __restrict__ bandNode) {
  int i = blockIdx.x * blockDim.x + threadIdx.x;
  if (i >= NN) return;
  u32 b = barr[i];
  u64 ki = key[i];
  u32 bs = base[b], cnt = bcnt[b];
  u32 off = NN - bs - cnt;
  u32 gt = 0;
  for (u32 j = 0; j < cnt; ++j) gt += (key[blist[off + j]] > ki) ? 1u : 0u;
  int r = (int)(bs + gt);
  arank[i] = r; // full approx rank (a permutation of 0..NN-1)
  int rb = r - (KK - BB);
  if (rb >= 0 && rb < 2 * BB) bandNode[rb] = (u32)i;
}

// ---------------- exact band repair ----------------
// exact f64 rescore via linearity: a = (sum_s wgt_s * x_s) @ W + bias
__global__ void k_bscore(const u32* __restrict__ bandNode,
                         const float* __restrict__ x, const float* __restrict__ w,
                         const double* __restrict__ dinv64,
                         const u32* __restrict__ offs, const u32* __restrict__ deg,
                         const int* __restrict__ csr, const float* __restrict__ bias,
                         u64* __restrict__ ekey) {
  __shared__ double zsh[4][DD]; // 4 KiB
  int wid = threadIdx.x >> 6;
  int lane = threadIdx.x & 63;
  int slot = blockIdx.x * 4 + wid;
  int node = (int)bandNode[slot];
  double di = dinv64[node];
  double z0 = 0.0, z1 = 0.0;
  u32 o = offs[node], cnt = deg[node];
  for (u32 k = 0; k <= cnt; ++k) { // last iter = self row
    int s = (k < cnt) ? csr[o + k] : node;
    double wgt = (k < cnt) ? (dinv64[s] * di) : (di * di);
    float2 xv = ((const float2*)x)[(size_t)s * 64 + lane];
    z0 += (double)xv.x * wgt;
    z1 += (double)xv.y * wgt;
  }
  zsh[wid][2 * lane] = z0;
  zsh[wid][2 * lane + 1] = z1;
  __syncthreads();
  float2 bv = ((const float2*)bias)[lane];
  double a0 = (double)bv.x, a1 = (double)bv.y;
  for (int kk = 0; kk < DD; ++kk) {
    double zk = zsh[wid][kk];
    float2 wv = ((const float2*)w)[kk * 64 + lane];
    a0 += zk * (double)wv.x;
    a1 += zk * (double)wv.y;
  }
  double ss = a0 * a0 + a1 * a1;
  #pragma unroll
  for (int off = 32; off > 0; off >>= 1) ss += __shfl_xor(ss, off);
  if (lane == 0) {
    double sc = sqrt(ss + 1e-12);
    u64 bits = (u64)__double_as_longlong(sc);
    ekey[slot] = (bits & ~0x1FFFFull) | (u64)(0x1FFFF - node);
  }
}

__global__ void k_bandrank(const u64* __restrict__ ekey, u32* __restrict__ brank) {
  __shared__ u64 sk[2 * BB]; // 32 KiB
  int t = threadIdx.x;
  for (int j = t; j < 2 * BB; j += 256) sk[j] = ekey[j];
  __syncthreads();
  int idx = blockIdx.x * 256 + t;
  u64 kk = sk[idx];
  u32 c = 0;
  for (int j = 0; j < 2 * BB; ++j) c += (sk[j] > kk) ? 1u : 0u;
  brank[idx] = c;
}

// ---------------- outputs (f32, bf16-RNE-quantized) ----------------
// 2 elems/thread: u32 (half2) load from hc16, float2 store; pos inlined
__global__ void k_xout(const u32* __restrict__ hc16, const float* __restrict__ gate,
                       const int* __restrict__ arank, const u32* __restrict__ brank,
                       float* __restrict__ outx) {
  int id = blockIdx.x * blockDim.x + threadIdx.x;
  if (id >= NN * 64) return;
  int i = id >> 6, d2 = id & 63;
  int p = posf(arank[i], brank);
  if (p < 0) return;
  float g = gate[i];
  u32 hv = hc16[(size_t)i * 64 + d2];
  float2 v = __half22float2(*(__half2*)&hv);
  float2 out = make_float2(bq(v.x * g), bq(v.y * g));
  ((float2*)outx)[(size_t)p * 64 + d2] = out;
}

// 2 edges/thread; pos inlined
__global__ void k_edges(const int* __restrict__ ei, const int* __restrict__ arank,
                        const u32* __restrict__ brank,
                        float* __restrict__ osrc, float* __restrict__ odst,
                        float* __restrict__ omask) {
  int e2 = blockIdx.x * blockDim.x + threadIdx.x;
  if (e2 >= EE / 2) return;
  int2 sv = ((const int2*)ei)[e2];
  int2 dv = ((const int2*)(ei + EE))[e2];
  int ps0 = posf(arank[sv.x], brank), pd0 = posf(arank[dv.x], brank);
  int ps1 = posf(arank[sv.y], brank), pd1 = posf(arank[dv.y], brank);
  bool m0 = (ps0 >= 0) && (pd0 >= 0);
  bool m1 = (ps1 >= 0) && (pd1 >= 0);
  ((float2*)osrc)[e2] = make_float2(m0 ? bq((float)ps0) : -1.0f,
                                    m1 ? bq((float)ps1) : -1.0f);
  ((float2*)odst)[e2] = make_float2(m0 ? bq((float)pd0) : -1.0f,
                                    m1 ? bq((float)pd1) : -1.0f);
  ((float2*)omask)[e2] = make_float2(m0 ? 1.0f : 0.0f, m1 ? 1.0f : 0.0f);
}

// ---------------- driver (16 dispatches) ----------------
extern "C" void kernel_launch(void* const* d_in, const int* in_sizes, int n_in,
                              void* d_out, int out_size, void* d_ws, size_t ws_size,
                              hipStream_t stream) {
  const float* x    = (const float*)d_in[0];
  const int*   ei   = (const int*)d_in[1];
  const float* w    = (const float*)d_in[2];
  const float* bias = (const float*)d_in[3];
  float* outx = (float*)d_out;
  char* ws = (char*)d_ws;

  size_t off = 0;
  auto alloc = [&](size_t b) -> void* {
    void* p = ws + off; off += (b + 255) & ~(size_t)255; return p;
  };
  u16*    hW16   = (u16*)alloc((size_t)NN * DD * 2);
  u32*    hc16   = (u32*)alloc((size_t)NN * DD * 2);
  double* dinv64 = (double*)alloc((size_t)NN * 8);
  float*  dinv32 = (float*)alloc((size_t)NN * 4);
  float*  gate   = (float*)alloc((size_t)NN * 4);
  u64*    key    = (u64*)alloc((size_t)NN * 8);
  u32*    deg    = (u32*)alloc((size_t)NN * 4);
  u32*    offs   = (u32*)alloc((size_t)NN * 4);
  int*    csr    = (int*)alloc((size_t)EE * 4);
  u32*    ebuf   = (u32*)alloc((size_t)EE * 4);
  u32*    chist  = (u32*)alloc((size_t)NBK * 4);
  u32*    cbase  = (u32*)alloc((size_t)NBK * 4);
  u32*    pbcur  = (u32*)alloc((size_t)NBK * 4);
  int*    arank  = (int*)alloc((size_t)NN * 4);
  u64*    meta   = (u64*)alloc(4 * 8);
  u32*    bcnt   = (u32*)alloc((size_t)NB * 4);
  u32*    base   = (u32*)alloc((size_t)NB * 4);
  u32*    bcur   = (u32*)alloc((size_t)NB * 4);
  u32*    barr   = (u32*)alloc((size_t)NN * 4);
  u32*    blist  = (u32*)alloc((size_t)NN * 4);
  u32*    bandNode = (u32*)alloc((size_t)2 * BB * 4);
  u64*    ekey     = (u64*)alloc((size_t)2 * BB * 8);
  u32*    brank    = (u32*)alloc((size_t)2 * BB * 4);
  f16x8*  wfrag    = (f16x8*)alloc((size_t)2048 * 16);

  k_init<<<256, 256, 0, stream>>>(w, wfrag, chist, bcnt, meta);
  // CSR build: coarse hist -> scan -> 2-pass partition (no global atomic storms)
  k_chist<<<(EE + TILE - 1) / TILE, 256, 0, stream>>>(ei, chist);
  k_cscan<<<1, 512, 0, stream>>>(chist, cbase, pbcur);
  k_part1<<<(EE + TILE - 1) / TILE, 256, 0, stream>>>(ei, pbcur, ebuf);
  k_part2<<<NBK, 256, 0, stream>>>(ebuf, cbase, deg, offs, dinv64, dinv32, csr);
  // GEMM via MFMA
  k_gemm_mfma<<<NN / 32, 256, 0, stream>>>(x, wfrag, hW16);
  // gather-aggregate + keys (no fusion — waves must retire freely)
  k_agg<<<NN / 16, 256, 0, stream>>>((const u32*)hW16, dinv32, offs, deg, csr,
                                     bias, hc16, key, gate);
  k_minmax<<<NBLK, 256, 0, stream>>>(key, meta);
  k_hist<<<(NN + 255) / 256, 256, 0, stream>>>(key, meta, barr, bcnt);
  k_bscan<<<1, 1024, 0, stream>>>(bcnt, base, bcur);
  k_bscatter<<<(NN + 255) / 256, 256, 0, stream>>>(barr, bcur, blist);
  k_rank2<<<(NN + 255) / 256, 256, 0, stream>>>(key, barr, bcnt, base, blist, arank,
                                                bandNode);
  // exact band repair (f64 truth via linearity)
  k_bscore<<<(2 * BB) / 4, 256, 0, stream>>>(bandNode, x, w, dinv64, offs, deg, csr,
                                             bias, ekey);
  k_bandrank<<<(2 * BB) / 256, 256, 0, stream>>>(ekey, brank);
  k_xout<<<(NN * 64 + 255) / 256, 256, 0, stream>>>(hc16, gate, arank, brank, outx);
  float* oei = outx + (size_t)KK * DD;
  k_edges<<<(EE / 2 + 255) / 256, 256, 0, stream>>>(ei, arank, brank, oei, oei + EE,
                                                    oei + 2 * (size_t)EE);
}

// Round 14
// 396.786 us; speedup vs baseline: 1.2846x; 1.1025x over previous
//
#include <hip/hip_runtime.h>
#include <hip/hip_fp16.h>
#include <stdint.h>

#define NN 100000
#define EE 3200000
#define DD 128
#define KK 50000
#define NB 32768    // rank buckets (2^15)
#define SBLK 128    // NB / 256
#define BB 2048     // band half-width around rank K (band size 2*BB)
#define NBK 391     // coarse edge buckets (256 dst nodes each)
#define TILE 8192   // edges per partition block
#define BMAX 12288  // max edges per coarse bucket staged in LDS (14 sigma)
#define NBLK 391    // ceil(NN / 256)

using u16 = unsigned short;
using u32 = unsigned int;
using u64 = unsigned long long;

typedef _Float16 f16x8 __attribute__((ext_vector_type(8)));
typedef float f32x4 __attribute__((ext_vector_type(4)));

// f32 -> bf16(RNE) -> f32, matching the harness's bf16-quantized reference.
__device__ __forceinline__ float bq(float f) {
  u32 b = __float_as_uint(f);
  b += 0x7FFFu + ((b >> 16) & 1u);
  return __uint_as_float(b & 0xFFFF0000u);
}

__device__ __forceinline__ u32 packh2(float a, float b) {
  return (u32)__half_as_ushort(__float2half(a)) |
         ((u32)__half_as_ushort(__float2half(b)) << 16);
}

// pos from approx rank + band rank (replaces the pos[] array)
__device__ __forceinline__ int posf(int r, const u32* __restrict__ brank) {
  if (r < KK - BB) return r;                       // surely kept
  if (r < KK + BB) {                               // band: exact order decides
    u32 br = brank[r - (KK - BB)];
    return (br < BB) ? (KK - BB + (int)br) : -1;
  }
  return -1;                                       // surely dropped
}

// ---------------- init + W-fragment prep (fused) ----------------
// wfrag[(kstep*8 + ctt)*64 + lane] = W[k][c], k=(lane>>4)*8+j+kstep*32, c=ctt*16+(lane&15)
__global__ void k_init(const float* __restrict__ w, f16x8* __restrict__ wfrag,
                       u32* __restrict__ chist, u32* __restrict__ bcnt,
                       u64* __restrict__ meta) {
  int i = blockIdx.x * 256 + threadIdx.x;
  for (int j = i; j < NB; j += 256 * 256) bcnt[j] = 0u;
  if (i < NBK) chist[i] = 0u;
  if (i == 0) { meta[0] = ~0ull; meta[1] = 0ull; }
  if (i < 2048) {
    int lane = i & 63;
    int ctt = (i >> 6) & 7;
    int kstep = i >> 9;
    int c = ctt * 16 + (lane & 15);
    int kbase = (lane >> 4) * 8 + kstep * 32;
    f16x8 v;
    #pragma unroll
    for (int j = 0; j < 8; ++j) v[j] = (_Float16)w[(kbase + j) * DD + c];
    wfrag[i] = v;
  }
}

// ---------------- coarse dst histogram (LDS-privatized, int4 loads) ----------------
__global__ void k_chist(const int* __restrict__ ei, u32* __restrict__ chist) {
  __shared__ u32 cnt[NBK];
  int t = threadIdx.x;
  int e0 = blockIdx.x * TILE;
  int vcnt = EE - e0; if (vcnt > TILE) vcnt = TILE; // always %4 == 0
  for (int i = t; i < NBK; i += 256) cnt[i] = 0;
  __syncthreads();
  const int4* dv = (const int4*)(ei + EE + e0);
  for (int i = t; i < (vcnt >> 2); i += 256) {
    int4 d = dv[i];
    atomicAdd(&cnt[(u32)d.x >> 8], 1u);
    atomicAdd(&cnt[(u32)d.y >> 8], 1u);
    atomicAdd(&cnt[(u32)d.z >> 8], 1u);
    atomicAdd(&cnt[(u32)d.w >> 8], 1u);
  }
  __syncthreads();
  for (int i = t; i < NBK; i += 256)
    if (cnt[i]) atomicAdd(&chist[i], cnt[i]);
}

// scan coarse histogram -> bucket bases (cbase) + partition cursors (pbcur)
__global__ void k_cscan(const u32* __restrict__ chist, u32* __restrict__ cbase,
                        u32* __restrict__ pbcur) {
  __shared__ u32 buf[2][512];
  int t = threadIdx.x;
  u32 v = (t < NBK) ? chist[t] : 0u;
  int a = 0; buf[0][t] = v; __syncthreads();
  for (int s = 1; s < 512; s <<= 1) {
    buf[1 - a][t] = buf[a][t] + ((t >= s) ? buf[a][t - s] : 0u);
    a = 1 - a; __syncthreads();
  }
  if (t < NBK) { u32 e = buf[a][t] - v; cbase[t] = e; pbcur[t] = e; }
}

// pass 1: partition edges into 391 coarse buckets (coalesced run flushes)
__global__ void k_part1(const int* __restrict__ ei, u32* __restrict__ bcur,
                        u32* __restrict__ ebuf) {
  __shared__ u32 cnt[NBK];
  __shared__ u32 lpos[NBK];
  __shared__ u32 gbase[NBK];
  __shared__ u32 sbuf[TILE];  // 32 KiB packed entries, bucket-sorted
  __shared__ u16 sbid[TILE];  // 16 KiB bucket id per slot
  int t = threadIdx.x;
  int e0 = blockIdx.x * TILE;
  int vcnt = EE - e0; if (vcnt > TILE) vcnt = TILE; // always %4 == 0
  for (int i = t; i < NBK; i += 256) cnt[i] = 0;
  __syncthreads();
  const int4* dv4 = (const int4*)(ei + EE + e0);
  for (int i = t; i < (vcnt >> 2); i += 256) {
    int4 d = dv4[i];
    atomicAdd(&cnt[(u32)d.x >> 8], 1u);
    atomicAdd(&cnt[(u32)d.y >> 8], 1u);
    atomicAdd(&cnt[(u32)d.z >> 8], 1u);
    atomicAdd(&cnt[(u32)d.w >> 8], 1u);
  }
  __syncthreads();
  // exclusive scan cnt -> lpos (wave 0, shfl segments of 64)
  if (t < 64) {
    u32 carry = 0;
    for (int c = 0; c < 7; ++c) {
      int idx = c * 64 + t;
      u32 v = (idx < NBK) ? cnt[idx] : 0u;
      u32 x = v;
      #pragma unroll
      for (int s = 1; s < 64; s <<= 1) {
        u32 y = __shfl_up(x, s);
        if (t >= s) x += y;
      }
      if (idx < NBK) lpos[idx] = x - v + carry;
      carry += __shfl(x, 63);
    }
  }
  __syncthreads();
  for (int i = t; i < NBK; i += 256)
    gbase[i] = cnt[i] ? atomicAdd(&bcur[i], cnt[i]) : 0u;
  // local scatter (bucket-sorted within the tile)
  for (int i = t; i < vcnt; i += 256) {
    int d = ei[EE + e0 + i];
    int s = ei[e0 + i];
    u32 b = (u32)d >> 8;
    u32 p = atomicAdd(&lpos[b], 1u);
    sbuf[p] = ((u32)(d & 255) << 17) | (u32)s;
    sbid[p] = (u16)b;
  }
  __syncthreads();
  // coalesced run flush
  for (int i = t; i < vcnt; i += 256) {
    u32 b = sbid[i];
    u32 lstart = lpos[b] - cnt[b];
    ebuf[gbase[b] + ((u32)i - lstart)] = sbuf[i];
  }
}

// pass 2: fine histogram + scan (deg/offs/dinv) + exact csr, all in LDS
__global__ void k_part2(const u32* __restrict__ ebuf, const u32* __restrict__ cbase,
                        u32* __restrict__ deg, u32* __restrict__ offs,
                        double* __restrict__ dinv64, float* __restrict__ dinv32,
                        int* __restrict__ csr) {
  __shared__ u32 fcnt[256];
  __shared__ u32 buf[2][256];
  __shared__ u32 ncur[256];
  __shared__ u32 scsr[BMAX]; // 48 KiB
  int b = blockIdx.x; int t = threadIdx.x;
  int nbase = b * 256;
  u32 gstart = cbase[b];
  u32 gend = (b + 1 < NBK) ? cbase[b + 1] : (u32)EE;
  u32 cnt = gend - gstart;
  fcnt[t] = 0u;
  __syncthreads();
  for (u32 i = t; i < cnt; i += 256)
    atomicAdd(&fcnt[ebuf[gstart + i] >> 17], 1u);
  __syncthreads();
  // exclusive scan of fcnt
  u32 v = fcnt[t];
  int a = 0; buf[0][t] = v; __syncthreads();
  for (int s = 1; s < 256; s <<= 1) {
    buf[1 - a][t] = buf[a][t] + ((t >= s) ? buf[a][t - s] : 0u);
    a = 1 - a; __syncthreads();
  }
  u32 floc = buf[a][t] - v;
  int node = nbase + t;
  if (node < NN) {
    deg[node] = v;
    offs[node] = gstart + floc;
    double d = 1.0 / sqrt((double)(v + 1u)); // +1 self-loop
    dinv64[node] = d;
    dinv32[node] = (float)d;
  }
  ncur[t] = floc;
  __syncthreads();
  if (cnt <= (u32)BMAX) {
    for (u32 i = t; i < cnt; i += 256) {
      u32 en = ebuf[gstart + i];
      u32 p = atomicAdd(&ncur[en >> 17], 1u);
      scsr[p] = en & 0x1FFFFu;
    }
    __syncthreads();
    for (u32 i = t; i < cnt; i += 256) csr[gstart + i] = (int)scsr[i];
  } else { // statistically unreachable fallback: direct global scatter
    for (u32 i = t; i < cnt; i += 256) {
      u32 en = ebuf[gstart + i];
      u32 p = atomicAdd(&ncur[en >> 17], 1u);
      csr[gstart + p] = (int)(en & 0x1FFFFu);
    }
  }
}

// ------- h = x @ W via MFMA 16x16x32 f16 (f32 accumulate, emit fp16) -------
__global__ void __launch_bounds__(256) k_gemm_mfma(const float* __restrict__ x,
                                                   const f16x8* __restrict__ wfrag,
                                                   u16* __restrict__ hW16) {
  int wid = threadIdx.x >> 6, lane = threadIdx.x & 63;
  int rowbase = blockIdx.x * 32 + (wid & 1) * 16;
  int colgrp = wid >> 1; // 0..1, 64 cols each
  int row = rowbase + (lane & 15);
  int klane = (lane >> 4) * 8;

  f32x4 acc[4] = {{0,0,0,0},{0,0,0,0},{0,0,0,0},{0,0,0,0}};
  const float* xr = x + (size_t)row * DD;
  #pragma unroll
  for (int kstep = 0; kstep < 4; ++kstep) {
    const float4* xp = (const float4*)(xr + klane + kstep * 32);
    float4 v0 = xp[0], v1 = xp[1];
    f16x8 a;
    a[0] = (_Float16)v0.x; a[1] = (_Float16)v0.y;
    a[2] = (_Float16)v0.z; a[3] = (_Float16)v0.w;
    a[4] = (_Float16)v1.x; a[5] = (_Float16)v1.y;
    a[6] = (_Float16)v1.z; a[7] = (_Float16)v1.w;
    #pragma unroll
    for (int ct = 0; ct < 4; ++ct) {
      f16x8 b = wfrag[(kstep * 8 + colgrp * 4 + ct) * 64 + lane];
      acc[ct] = __builtin_amdgcn_mfma_f32_16x16x32_f16(a, b, acc[ct], 0, 0, 0);
    }
  }
  #pragma unroll
  for (int ct = 0; ct < 4; ++ct) {
    int col = colgrp * 64 + ct * 16 + (lane & 15);
    #pragma unroll
    for (int reg = 0; reg < 4; ++reg) {
      int r = rowbase + (lane >> 4) * 4 + reg;
      hW16[(size_t)r * DD + col] = __half_as_ushort(__float2half(acc[ct][reg]));
    }
  }
}

// ---- gather-aggregate: 4 nodes/wave (16 lanes/node, 8 dims/lane via uint4) ----
// NO trailing barrier/fusion (round-12 lesson: parked waves kill gather overlap).
__global__ void k_agg(const u32* __restrict__ hw, const float* __restrict__ dinv32,
                      const u32* __restrict__ offs, const u32* __restrict__ deg,
                      const int* __restrict__ csr, const float* __restrict__ bias,
                      u32* __restrict__ hc16, u64* __restrict__ key,
                      float* __restrict__ gate) {
  int t = threadIdx.x;
  int l4 = t & 15;             // handles dims 8*l4 .. 8*l4+7
  int node = blockIdx.x * 16 + (t >> 4);
  if (node >= NN) return;
  const uint4* hwp = (const uint4*)hw;
  float di = dinv32[node];
  float a0 = 0.f, a1 = 0.f, a2 = 0.f, a3 = 0.f;
  float a4 = 0.f, a5 = 0.f, a6 = 0.f, a7 = 0.f;
  u32 o = offs[node], cnt = deg[node];
  u32 k = 0;
  for (; k + 2 <= cnt; k += 2) {
    int s0 = csr[o + k], s1 = csr[o + k + 1];
    float n0 = dinv32[s0] * di, n1 = dinv32[s1] * di;
    uint4 w0 = hwp[(size_t)s0 * 16 + l4];
    uint4 w1 = hwp[(size_t)s1 * 16 + l4];
    float2 p00 = __half22float2(*(__half2*)&w0.x), p01 = __half22float2(*(__half2*)&w0.y);
    float2 p02 = __half22float2(*(__half2*)&w0.z), p03 = __half22float2(*(__half2*)&w0.w);
    float2 p10 = __half22float2(*(__half2*)&w1.x), p11 = __half22float2(*(__half2*)&w1.y);
    float2 p12 = __half22float2(*(__half2*)&w1.z), p13 = __half22float2(*(__half2*)&w1.w);
    a0 += p00.x * n0 + p10.x * n1;
    a1 += p00.y * n0 + p10.y * n1;
    a2 += p01.x * n0 + p11.x * n1;
    a3 += p01.y * n0 + p11.y * n1;
    a4 += p02.x * n0 + p12.x * n1;
    a5 += p02.y * n0 + p12.y * n1;
    a6 += p03.x * n0 + p13.x * n1;
    a7 += p03.y * n0 + p13.y * n1;
  }
  for (; k < cnt; ++k) {
    int s = csr[o + k];
    float nrm = dinv32[s] * di;
    uint4 wb = hwp[(size_t)s * 16 + l4];
    float2 p0 = __half22float2(*(__half2*)&wb.x), p1 = __half22float2(*(__half2*)&wb.y);
    float2 p2 = __half22float2(*(__half2*)&wb.z), p3 = __half22float2(*(__half2*)&wb.w);
    a0 += p0.x * nrm; a1 += p0.y * nrm; a2 += p1.x * nrm; a3 += p1.y * nrm;
    a4 += p2.x * nrm; a5 += p2.y * nrm; a6 += p3.x * nrm; a7 += p3.y * nrm;
  }
  float di2 = di * di;
  uint4 wb = hwp[(size_t)node * 16 + l4];
  float2 p0 = __half22float2(*(__half2*)&wb.x), p1 = __half22float2(*(__half2*)&wb.y);
  float2 p2 = __half22float2(*(__half2*)&wb.z), p3 = __half22float2(*(__half2*)&wb.w);
  float4 bv0 = ((const float4*)bias)[2 * l4];
  float4 bv1 = ((const float4*)bias)[2 * l4 + 1];
  a0 += p0.x * di2 + bv0.x;
  a1 += p0.y * di2 + bv0.y;
  a2 += p1.x * di2 + bv0.z;
  a3 += p1.y * di2 + bv0.w;
  a4 += p2.x * di2 + bv1.x;
  a5 += p2.y * di2 + bv1.y;
  a6 += p3.x * di2 + bv1.z;
  a7 += p3.y * di2 + bv1.w;
  uint4 out;
  out.x = packh2(a0, a1); out.y = packh2(a2, a3);
  out.z = packh2(a4, a5); out.w = packh2(a6, a7);
  ((uint4*)hc16)[(size_t)node * 16 + l4] = out;
  float ss = a0 * a0 + a1 * a1 + a2 * a2 + a3 * a3
           + a4 * a4 + a5 * a5 + a6 * a6 + a7 * a7;
  #pragma unroll
  for (int off = 8; off > 0; off >>= 1) ss += __shfl_xor(ss, off);
  if (l4 == 0) {
    // approx key: f32 ss bits (monotone in score, ss >= 0);
    // low 17 bits = (0x1FFFF - node) => lower index wins ties
    u32 sb = __float_as_uint(ss);
    key[node] = ((u64)sb << 17) | (u64)(0x1FFFF - node);
    gate[node] = tanhf(sqrtf(ss + 1e-12f));
  }
}

// ---------------- key min/max (separate pass; round-12 lesson) ----------------
__global__ void k_minmax(const u64* __restrict__ key, u64* __restrict__ meta) {
  __shared__ u64 smn[256], smx[256];
  int t = threadIdx.x; int i = blockIdx.x * 256 + t;
  u64 v = (i < NN) ? key[i] : key[0];
  smn[t] = v; smx[t] = v; __syncthreads();
  for (int s = 128; s > 0; s >>= 1) {
    if (t < s) {
      if (smn[t + s] < smn[t]) smn[t] = smn[t + s];
      if (smx[t + s] > smx[t]) smx[t] = smx[t + s];
    }
    __syncthreads();
  }
  if (t == 0) { atomicMin(&meta[0], smn[0]); atomicMax(&meta[1], smx[0]); }
}

// ---------------- exact bucket-rank (approx keys -> full rank) ----------------
__device__ __forceinline__ u32 bshift(u64 kmin, u64 kmax) {
  u64 range = kmax - kmin;
  int bits = 64 - __clzll(range | 1ull);
  return (u32)(bits > 15 ? bits - 15 : 0); // 2^15 buckets
}

__global__ void k_hist(const u64* __restrict__ key, const u64* __restrict__ meta,
                       u32* __restrict__ barr, u32* __restrict__ bcnt) {
  int i = blockIdx.x * blockDim.x + threadIdx.x;
  if (i >= NN) return;
  u64 kmin = meta[0];
  u32 sh = bshift(kmin, meta[1]);
  u32 b = (u32)((key[i] - kmin) >> sh);
  barr[i] = b;
  atomicAdd(&bcnt[b], 1u);
}

// parallel suffix-scan over NB buckets (3 small kernels — round-13 lesson:
// the fused single-block version serialized ~30us on one CU)
__global__ void k_bscan1(const u32* __restrict__ bcnt, u32* __restrict__ bsum2) {
  __shared__ u32 sh[256];
  int t = threadIdx.x; int r = blockIdx.x * 256 + t;
  u32 v = bcnt[NB - 1 - r];
  sh[t] = v; __syncthreads();
  for (int s = 128; s > 0; s >>= 1) { if (t < s) sh[t] += sh[t + s]; __syncthreads(); }
  if (t == 0) bsum2[blockIdx.x] = sh[0];
}

__global__ void k_scan2(u32* __restrict__ bsum, int nb) { // 1 block, 512 thr, nb<=512
  __shared__ u32 buf[2][512];
  int t = threadIdx.x;
  u32 v = (t < nb) ? bsum[t] : 0u;
  int a = 0; buf[0][t] = v; __syncthreads();
  for (int s = 1; s < 512; s <<= 1) {
    buf[1 - a][t] = buf[a][t] + ((t >= s) ? buf[a][t - s] : 0u);
    a = 1 - a; __syncthreads();
  }
  if (t < nb) bsum[t] = buf[a][t] - v; // exclusive
}

__global__ void k_bscan3(const u32* __restrict__ bcnt, const u32* __restrict__ bsum2,
                         u32* __restrict__ base, u32* __restrict__ bcur) {
  __shared__ u32 buf[2][256];
  int t = threadIdx.x; int r = blockIdx.x * 256 + t;
  int b = NB - 1 - r;
  u32 v = bcnt[b];
  int a = 0; buf[0][t] = v; __syncthreads();
  for (int s = 1; s < 256; s <<= 1) {
    buf[1 - a][t] = buf[a][t] + ((t >= s) ? buf[a][t - s] : 0u);
    a = 1 - a; __syncthreads();
  }
  u32 bs = buf[a][t] - v + bsum2[blockIdx.x]; // suffix-exclusive
  base[b] = bs;
  bcur[b] = NN - bs - v;
}

__global__ void k_bscatter(const u32* __restrict__ barr, u32* __restrict__ bcur,
                           u32* __restrict__ blist) {
  int i = blockIdx.x * blockDim.x + threadIdx.x;
  if (i >= NN) return;
  u32 p = atomicAdd(&bcur[barr[i]], 1u);
  blist[p] = (u32)i;
}

// rank + in-band selection fused
__global__ void k_rank2(const u64* __restrict__ key, const u32* __restrict__ barr,
                        const u32* __restrict__ bcnt, const u32* __restrict__ base,
                        const u32* __restrict__ blist, int* __restrict__ arank,
                        u32* __restrict__ bandNode) {
  int i = blockIdx.x * blockDim.x + threadIdx.x;
  if (i >= NN) return;
  u32 b = barr[i];
  u64 ki = key[i];
  u32 bs = base[b], cnt = bcnt[b];
  u32 off = NN - bs - cnt;
  u32 gt = 0;
  for (u32 j = 0; j < cnt; ++j) gt += (key[blist[off + j]] > ki) ? 1u : 0u;
  int r = (int)(bs + gt);
  arank[i] = r; // full approx rank (a permutation of 0..NN-1)
  int rb = r - (KK - BB);
  if (rb >= 0 && rb < 2 * BB) bandNode[rb] = (u32)i;
}

// ---------------- exact band repair ----------------
// exact f64 rescore via linearity: a = (sum_s wgt_s * x_s) @ W + bias
__global__ void k_bscore(const u32* __restrict__ bandNode,
                         const float* __restrict__ x, const float* __restrict__ w,
                         const double* __restrict__ dinv64,
                         const u32* __restrict__ offs, const u32* __restrict__ deg,
                         const int* __restrict__ csr, const float* __restrict__ bias,
                         u64* __restrict__ ekey) {
  __shared__ double zsh[4][DD]; // 4 KiB
  int wid = threadIdx.x >> 6;
  int lane = threadIdx.x & 63;
  int slot = blockIdx.x * 4 + wid;
  int node = (int)bandNode[slot];
  double di = dinv64[node];
  double z0 = 0.0, z1 = 0.0;
  u32 o = offs[node], cnt = deg[node];
  for (u32 k = 0; k <= cnt; ++k) { // last iter = self row
    int s = (k < cnt) ? csr[o + k] : node;
    double wgt = (k < cnt) ? (dinv64[s] * di) : (di * di);
    float2 xv = ((const float2*)x)[(size_t)s * 64 + lane];
    z0 += (double)xv.x * wgt;
    z1 += (double)xv.y * wgt;
  }
  zsh[wid][2 * lane] = z0;
  zsh[wid][2 * lane + 1] = z1;
  __syncthreads();
  float2 bv = ((const float2*)bias)[lane];
  double a0 = (double)bv.x, a1 = (double)bv.y;
  for (int kk = 0; kk < DD; ++kk) {
    double zk = zsh[wid][kk];
    float2 wv = ((const float2*)w)[kk * 64 + lane];
    a0 += zk * (double)wv.x;
    a1 += zk * (double)wv.y;
  }
  double ss = a0 * a0 + a1 * a1;
  #pragma unroll
  for (int off = 32; off > 0; off >>= 1) ss += __shfl_xor(ss, off);
  if (lane == 0) {
    double sc = sqrt(ss + 1e-12);
    u64 bits = (u64)__double_as_longlong(sc);
    ekey[slot] = (bits & ~0x1FFFFull) | (u64)(0x1FFFF - node);
  }
}

__global__ void k_bandrank(const u64* __restrict__ ekey, u32* __restrict__ brank) {
  __shared__ u64 sk[2 * BB]; // 32 KiB
  int t = threadIdx.x;
  for (int j = t; j < 2 * BB; j += 256) sk[j] = ekey[j];
  __syncthreads();
  int idx = blockIdx.x * 256 + t;
  u64 kk = sk[idx];
  u32 c = 0;
  for (int j = 0; j < 2 * BB; ++j) c += (sk[j] > kk) ? 1u : 0u;
  brank[idx] = c;
}

// ---------------- outputs (f32, bf16-RNE-quantized) ----------------
// 2 elems/thread: u32 (half2) load from hc16, float2 store; pos inlined
__global__ void k_xout(const u32* __restrict__ hc16, const float* __restrict__ gate,
                       const int* __restrict__ arank, const u32* __restrict__ brank,
                       float* __restrict__ outx) {
  int id = blockIdx.x * blockDim.x + threadIdx.x;
  if (id >= NN * 64) return;
  int i = id >> 6, d2 = id & 63;
  int p = posf(arank[i], brank);
  if (p < 0) return;
  float g = gate[i];
  u32 hv = hc16[(size_t)i * 64 + d2];
  float2 v = __half22float2(*(__half2*)&hv);
  float2 out = make_float2(bq(v.x * g), bq(v.y * g));
  ((float2*)outx)[(size_t)p * 64 + d2] = out;
}

// 2 edges/thread; pos inlined
__global__ void k_edges(const int* __restrict__ ei, const int* __restrict__ arank,
                        const u32* __restrict__ brank,
                        float* __restrict__ osrc, float* __restrict__ odst,
                        float* __restrict__ omask) {
  int e2 = blockIdx.x * blockDim.x + threadIdx.x;
  if (e2 >= EE / 2) return;
  int2 sv = ((const int2*)ei)[e2];
  int2 dv = ((const int2*)(ei + EE))[e2];
  int ps0 = posf(arank[sv.x], brank), pd0 = posf(arank[dv.x], brank);
  int ps1 = posf(arank[sv.y], brank), pd1 = posf(arank[dv.y], brank);
  bool m0 = (ps0 >= 0) && (pd0 >= 0);
  bool m1 = (ps1 >= 0) && (pd1 >= 0);
  ((float2*)osrc)[e2] = make_float2(m0 ? bq((float)ps0) : -1.0f,
                                    m1 ? bq((float)ps1) : -1.0f);
  ((float2*)odst)[e2] = make_float2(m0 ? bq((float)pd0) : -1.0f,
                                    m1 ? bq((float)pd1) : -1.0f);
  ((float2*)omask)[e2] = make_float2(m0 ? 1.0f : 0.0f, m1 ? 1.0f : 0.0f);
}

// ---------------- driver (18 dispatches) ----------------
extern "C" void kernel_launch(void* const* d_in, const int* in_sizes, int n_in,
                              void* d_out, int out_size, void* d_ws, size_t ws_size,
                              hipStream_t stream) {
  const float* x    = (const float*)d_in[0];
  const int*   ei   = (const int*)d_in[1];
  const float* w    = (const float*)d_in[2];
  const float* bias = (const float*)d_in[3];
  float* outx = (float*)d_out;
  char* ws = (char*)d_ws;

  size_t off = 0;
  auto alloc = [&](size_t b) -> void* {
    void* p = ws + off; off += (b + 255) & ~(size_t)255; return p;
  };
  u16*    hW16   = (u16*)alloc((size_t)NN * DD * 2);
  u32*    hc16   = (u32*)alloc((size_t)NN * DD * 2);
  double* dinv64 = (double*)alloc((size_t)NN * 8);
  float*  dinv32 = (float*)alloc((size_t)NN * 4);
  float*  gate   = (float*)alloc((size_t)NN * 4);
  u64*    key    = (u64*)alloc((size_t)NN * 8);
  u32*    deg    = (u32*)alloc((size_t)NN * 4);
  u32*    offs   = (u32*)alloc((size_t)NN * 4);
  int*    csr    = (int*)alloc((size_t)EE * 4);
  u32*    ebuf   = (u32*)alloc((size_t)EE * 4);
  u32*    chist  = (u32*)alloc((size_t)NBK * 4);
  u32*    cbase  = (u32*)alloc((size_t)NBK * 4);
  u32*    pbcur  = (u32*)alloc((size_t)NBK * 4);
  int*    arank  = (int*)alloc((size_t)NN * 4);
  u64*    meta   = (u64*)alloc(4 * 8);
  u32*    bcnt   = (u32*)alloc((size_t)NB * 4);
  u32*    base   = (u32*)alloc((size_t)NB * 4);
  u32*    bcur   = (u32*)alloc((size_t)NB * 4);
  u32*    bsum2  = (u32*)alloc(SBLK * 4);
  u32*    barr   = (u32*)alloc((size_t)NN * 4);
  u32*    blist  = (u32*)alloc((size_t)NN * 4);
  u32*    bandNode = (u32*)alloc((size_t)2 * BB * 4);
  u64*    ekey     = (u64*)alloc((size_t)2 * BB * 8);
  u32*    brank    = (u32*)alloc((size_t)2 * BB * 4);
  f16x8*  wfrag    = (f16x8*)alloc((size_t)2048 * 16);

  k_init<<<256, 256, 0, stream>>>(w, wfrag, chist, bcnt, meta);
  // CSR build: coarse hist -> scan -> 2-pass partition
  k_chist<<<(EE + TILE - 1) / TILE, 256, 0, stream>>>(ei, chist);
  k_cscan<<<1, 512, 0, stream>>>(chist, cbase, pbcur);
  k_part1<<<(EE + TILE - 1) / TILE, 256, 0, stream>>>(ei, pbcur, ebuf);
  k_part2<<<NBK, 256, 0, stream>>>(ebuf, cbase, deg, offs, dinv64, dinv32, csr);
  // GEMM via MFMA
  k_gemm_mfma<<<NN / 32, 256, 0, stream>>>(x, wfrag, hW16);
  // gather-aggregate + keys
  k_agg<<<NN / 16, 256, 0, stream>>>((const u32*)hW16, dinv32, offs, deg, csr,
                                     bias, hc16, key, gate);
  k_minmax<<<NBLK, 256, 0, stream>>>(key, meta);
  k_hist<<<(NN + 255) / 256, 256, 0, stream>>>(key, meta, barr, bcnt);
  k_bscan1<<<SBLK, 256, 0, stream>>>(bcnt, bsum2);
  k_scan2<<<1, 512, 0, stream>>>(bsum2, SBLK);
  k_bscan3<<<SBLK, 256, 0, stream>>>(bcnt, bsum2, base, bcur);
  k_bscatter<<<(NN + 255) / 256, 256, 0, stream>>>(barr, bcur, blist);
  k_rank2<<<(NN + 255) / 256, 256, 0, stream>>>(key, barr, bcnt, base, blist, arank,
                                                bandNode);
  // exact band repair (f64 truth via linearity)
  k_bscore<<<(2 * BB) / 4, 256, 0, stream>>>(bandNode, x, w, dinv64, offs, deg, csr,
                                             bias, ekey);
  k_bandrank<<<(2 * BB) / 256, 256, 0, stream>>>(ekey, brank);
  k_xout<<<(NN * 64 + 255) / 256, 256, 0, stream>>>(hc16, gate, arank, brank, outx);
  float* oei = outx + (size_t)KK * DD;
  k_edges<<<(EE / 2 + 255) / 256, 256, 0, stream>>>(ei, arank, brank, oei, oei + EE,
                                                    oei + 2 * (size_t)EE);
}